// Round 5
// baseline (98.832 us; speedup 1.0000x reference)
//
#include <hip/hip_runtime.h>
#include <hip/hip_bf16.h>

#define NN 8192
#define NB 8192                               // value buckets over [0,1)
#define EPSF 1e-8f
#define LOG2E 1.4426950408889634f
#define LN2f 0.6931471805599453f
#define BLOCK 256
#define CHUNKS 4
#define CH (NN / CHUNKS)                      // 2048 j-elements per chunk
#define RG (NN / 16)                          // 512 row-groups (16 sorted positions each)
#define A2SCALE (20.0f * LOG2E)               // (pred/0.05)*log2(e)

// ---------------------------------------------------------------------------
// Kernel 1: single-block counting sort of yt (ascending by bucket; within-
// bucket order arbitrary — loss is permutation-invariant, and straddle zones
// get the exact compare). Outputs ybkt[], a2bkt[] (pre-scaled pred), offs[].
// ---------------------------------------------------------------------------
__global__ __launch_bounds__(1024) void sort_kernel(const float* __restrict__ yt,
                                                    const float* __restrict__ pred,
                                                    float* __restrict__ ybkt,
                                                    float* __restrict__ a2bkt,
                                                    int* __restrict__ offs) {
    __shared__ int hist[NB];                  // 32 KB
    __shared__ int wsum[16], wexcl[16];
    const int t = threadIdx.x, lane = t & 63, wave = t >> 6;

    for (int k = t; k < NB; k += 1024) hist[k] = 0;
    __syncthreads();

    float yv[8]; int bv[8];
#pragma unroll
    for (int k = 0; k < 8; ++k) {
        int i = t + k * 1024;
        float y = yt[i];
        int b = min((int)(y * 8192.0f), NB - 1);
        yv[k] = y; bv[k] = b;
        atomicAdd(&hist[b], 1);
    }
    __syncthreads();

    // exclusive scan of hist (8 buckets/thread -> wave scan -> 16-wave scan)
    int local[8]; int sum = 0;
#pragma unroll
    for (int k = 0; k < 8; ++k) { local[k] = hist[t * 8 + k]; sum += local[k]; }
    int incl = sum;
    for (int d = 1; d < 64; d <<= 1) {
        int n = __shfl_up(incl, d);
        if (lane >= d) incl += n;
    }
    if (lane == 63) wsum[wave] = incl;
    __syncthreads();
    if (t < 16) {
        int v = wsum[t], inc2 = v;
        for (int d = 1; d < 16; d <<= 1) {
            int n = __shfl_up(inc2, d);
            if (t >= d) inc2 += n;
        }
        wexcl[t] = inc2 - v;
    }
    __syncthreads();
    int run = wexcl[wave] + incl - sum;       // exclusive base for this thread's buckets
#pragma unroll
    for (int k = 0; k < 8; ++k) {
        hist[t * 8 + k] = run;                // becomes the scatter cursor
        offs[t * 8 + k] = run;
        run += local[k];
    }
    if (t == 1023) offs[NB] = run;            // == NN
    __syncthreads();

    // scatter
#pragma unroll
    for (int k = 0; k < 8; ++k) {
        int i = t + k * 1024;
        int pos = atomicAdd(&hist[bv[k]], 1);
        ybkt[pos] = yv[k];
        a2bkt[pos] = pred[i] * A2SCALE;
    }
}

// ---------------------------------------------------------------------------
// Kernel 2: chunk-partial masked max + logsumexp over the sorted prefix.
// Block (rg, c): sorted positions [rg*16, rg*16+16) x j in [c*2048,(c+1)*2048).
// Unmasked region (buckets <= bp-2 for all 4 rows of the wave): 2 ops/pair.
// Masked straddle (exact fsub compare): few elements. Writes partial[c][p].
// ---------------------------------------------------------------------------
__global__ __launch_bounds__(BLOCK) void pro_main(const float* __restrict__ ybkt,
                                                  const float* __restrict__ a2bkt,
                                                  const int* __restrict__ offs,
                                                  float2* __restrict__ partial) {
    const int t = threadIdx.x;
    const int rg = blockIdx.x >> 2;
    const int c  = blockIdx.x & 3;
    const int j0 = c * CH;
    const int wave = t >> 6, lane = t & 63;
    const int row0 = rg * 16 + wave * 4;

    // whole-block inactive test (end is monotone in sorted position)
    {
        float xl = ybkt[rg * 16 + 15];
        int bl = min((int)(xl * 8192.0f), NB - 1);
        if (offs[bl + 1] <= j0) {
            if (lane == 0) {
#pragma unroll
                for (int r = 0; r < 4; ++r)
                    partial[c * NN + row0 + r] = make_float2(-INFINITY, 0.0f);
            }
            return;                           // uniform: no syncthreads skipped
        }
    }

    float x[4], M[4];
#pragma unroll
    for (int r = 0; r < 4; ++r) { x[r] = ybkt[row0 + r]; M[r] = -INFINITY; }
    int u0, end3;
    {
        int b0 = min((int)(x[0] * 8192.0f), NB - 1);
        u0 = (b0 > 0) ? offs[b0 - 1] : 0;     // below this: valid for ALL 4 rows
        int b3 = min((int)(x[3] * 8192.0f), NB - 1);
        end3 = offs[b3 + 1];                  // at/after this: invalid for all
    }
    int lo = min(max(u0 - j0, 0), CH);
    const int nbi = lo >> 7;                  // full 128-elem unmasked iters
    lo = nbi << 7;
    const int hi = min(max(end3 - j0, lo), CH);
    const int stage_n = min(CH, (hi + 127) & ~127);

    __shared__ float y_s[CH];                 // 8 KB
    __shared__ float4 ac_s[CH / 2];           // 16 KB: (a0, a0*y0, a1, a1*y1)
    const float4* yb4 = (const float4*)(ybkt + j0);
    const float4* ab4 = (const float4*)(a2bkt + j0);
    float4* ys4 = (float4*)y_s;
    for (int i = t; i < stage_n / 4; i += BLOCK) {
        float4 y4 = yb4[i];
        float4 a4 = ab4[i];
        ys4[i] = y4;
        ac_s[2 * i]     = make_float4(a4.x, a4.x * y4.x, a4.y, a4.y * y4.y);
        ac_s[2 * i + 1] = make_float4(a4.z, a4.z * y4.z, a4.w, a4.w * y4.w);
    }
    __syncthreads();

    // ---- pass 1: max of L = fma(a, x, -c) over the valid set ----
    for (int i = 0; i < nbi; ++i) {
        float4 v = ac_s[i * 64 + lane];       // elems 2*(i*64+lane), +1
#pragma unroll
        for (int r = 0; r < 4; ++r) {
            float L0 = __builtin_fmaf(v.x, x[r], -v.y);
            float L1 = __builtin_fmaf(v.z, x[r], -v.w);
            M[r] = fmaxf(M[r], fmaxf(L0, L1));
        }
    }
    for (int base = lo; base < hi; base += 128) {   // straddle: exact compare
        int e = base + lane * 2;
        float y0 = y_s[e], y1 = y_s[e + 1];
        float4 v = ac_s[(base >> 1) + lane];
#pragma unroll
        for (int r = 0; r < 4; ++r) {
            float W0 = x[r] - y0, W1 = x[r] - y1;
            float L0 = __builtin_fmaf(v.x, x[r], -v.y);
            float L1 = __builtin_fmaf(v.z, x[r], -v.w);
            L0 = (W0 > EPSF) ? L0 : -INFINITY;
            L1 = (W1 > EPSF) ? L1 : -INFINITY;
            M[r] = fmaxf(M[r], fmaxf(L0, L1));
        }
    }
#pragma unroll
    for (int r = 0; r < 4; ++r)
        for (int m = 1; m < 64; m <<= 1) M[r] = fmaxf(M[r], __shfl_xor(M[r], m));

    // ---- pass 2: sum exp2(L - M) over the same set ----
    float s[4] = {0.f, 0.f, 0.f, 0.f};
    for (int i = 0; i < nbi; ++i) {
        float4 v = ac_s[i * 64 + lane];
#pragma unroll
        for (int r = 0; r < 4; ++r) {
            float t0 = __builtin_fmaf(v.x, x[r], -v.y) - M[r];
            float t1 = __builtin_fmaf(v.z, x[r], -v.w) - M[r];
            s[r] += exp2f(t0) + exp2f(t1);
        }
    }
    for (int base = lo; base < hi; base += 128) {
        int e = base + lane * 2;
        float y0 = y_s[e], y1 = y_s[e + 1];
        float4 v = ac_s[(base >> 1) + lane];
#pragma unroll
        for (int r = 0; r < 4; ++r) {
            float W0 = x[r] - y0, W1 = x[r] - y1;
            float t0 = __builtin_fmaf(v.x, x[r], -v.y) - M[r];
            float t1 = __builtin_fmaf(v.z, x[r], -v.w) - M[r];
            t0 = (W0 > EPSF) ? t0 : -INFINITY;
            t1 = (W1 > EPSF) ? t1 : -INFINITY;
            s[r] += exp2f(t0) + exp2f(t1);
        }
    }
#pragma unroll
    for (int r = 0; r < 4; ++r)
        for (int m = 1; m < 64; m <<= 1) s[r] += __shfl_xor(s[r], m);

    if (lane == 0) {
#pragma unroll
        for (int r = 0; r < 4; ++r)
            partial[c * NN + row0 + r] = make_float2(M[r], s[r]);
    }
}

// ---------------------------------------------------------------------------
// Kernel 3: ymin, per-row combine of 4 chunk partials, epilogue, final scalar.
// Inactive chunks hold (-inf, 0): 0 * exp2(-inf - M) = 0 — harmless.
// ---------------------------------------------------------------------------
__global__ __launch_bounds__(1024) void finalize(const float* __restrict__ ybkt,
                                                 const float* __restrict__ a2bkt,
                                                 const float2* __restrict__ partial,
                                                 float* __restrict__ out) {
    __shared__ float redm[16];
    __shared__ float2 red2[16];
    __shared__ float bmin;
    const int t = threadIdx.x, lane = t & 63, wave = t >> 6;

    float mn = INFINITY;
    for (int i = t; i < NN; i += 1024) mn = fminf(mn, ybkt[i]);
#pragma unroll
    for (int m = 1; m < 64; m <<= 1) mn = fminf(mn, __shfl_xor(mn, m));
    if (lane == 0) redm[wave] = mn;
    __syncthreads();
    if (t == 0) {
        float v = redm[0];
        for (int i = 1; i < 16; ++i) v = fminf(v, redm[i]);
        bmin = v;
    }
    __syncthreads();
    const float yt_min = bmin;

    float wtot = 0.f, wcnt = 0.f;
    for (int p = t; p < NN; p += 1024) {
        float x = ybkt[p];
        float w = x - yt_min;                 // == weight_k (max masked gap)
        float lp = a2bkt[p] * w;              // logit_pos, log2-scaled
        float2 pc[CHUNKS];
        float M = lp;
#pragma unroll
        for (int c = 0; c < CHUNKS; ++c) {
            pc[c] = partial[c * NN + p];
            M = fmaxf(M, pc[c].x);
        }
        float sum = exp2f(lp - M);
#pragma unroll
        for (int c = 0; c < CHUNKS; ++c) sum += pc[c].y * exp2f(pc[c].x - M);
        float logp = (lp - M) * LN2f - __logf(sum);
        if (w > EPSF) { wtot += logp; wcnt += 1.f; }
    }
#pragma unroll
    for (int m = 1; m < 64; m <<= 1) { wtot += __shfl_xor(wtot, m); wcnt += __shfl_xor(wcnt, m); }
    if (lane == 0) red2[wave] = make_float2(wtot, wcnt);
    __syncthreads();
    if (t == 0) {
        float bt = 0.f, bc = 0.f;
        for (int i = 0; i < 16; ++i) { bt += red2[i].x; bc += red2[i].y; }
        out[0] = (bc > 0.f) ? (-bt / bc) : 0.f;
    }
}

extern "C" void kernel_launch(void* const* d_in, const int* in_sizes, int n_in,
                              void* d_out, int out_size, void* d_ws, size_t ws_size,
                              hipStream_t stream) {
    const float* pred = (const float*)d_in[0];  // predict_similarity
    const float* yt   = (const float*)d_in[1];  // true_similarity

    float* ybkt  = (float*)d_ws;                // [NN]
    float* a2bkt = ybkt + NN;                   // [NN]
    int*   offs  = (int*)(a2bkt + NN);          // [NN+2] (padded for alignment)
    float2* partial = (float2*)(offs + NN + 2); // [CHUNKS][NN] — fully overwritten

    sort_kernel<<<1, 1024, 0, stream>>>(yt, pred, ybkt, a2bkt, offs);
    pro_main<<<RG * CHUNKS, BLOCK, 0, stream>>>(ybkt, a2bkt, offs, partial);
    finalize<<<1, 1024, 0, stream>>>(ybkt, a2bkt, partial, (float*)d_out);
}

// Round 6
// 95.520 us; speedup vs baseline: 1.0347x; 1.0347x over previous
//
#include <hip/hip_runtime.h>
#include <hip/hip_bf16.h>

#define NN 8192
#define NB 8192                               // value buckets over [0,1)
#define EPSF 1e-8f
#define LOG2E 1.4426950408889634f
#define LN2f 0.6931471805599453f
#define BLOCK 256
#define CHUNKS 4
#define CH (NN / CHUNKS)                      // 2048 j-elements per chunk
#define RG (NN / 16)                          // 512 row-groups (16 sorted positions each)
#define A2SCALE (20.0f * LOG2E)               // (pred/0.05)*log2(e)

// ---------------------------------------------------------------------------
// Parallel counting sort, split wide: memset(hist) -> khist(32 blocks) ->
// kscan(1 block, tiny) -> kscatter(32 blocks). Within-bucket order arbitrary
// (loss is permutation-invariant; straddle zones get the exact compare).
// ---------------------------------------------------------------------------
__global__ __launch_bounds__(256) void khist(const float* __restrict__ yt,
                                             int* __restrict__ hist) {
    int i = blockIdx.x * 256 + threadIdx.x;
    float y = yt[i];
    int b = min(max((int)(y * 8192.0f), 0), NB - 1);
    atomicAdd(&hist[b], 1);
}

__global__ __launch_bounds__(1024) void kscan(const int* __restrict__ hist,
                                              int* __restrict__ offs,
                                              int* __restrict__ cursor) {
    __shared__ int wsum[16], wexcl[16];
    const int t = threadIdx.x, lane = t & 63, wave = t >> 6;

    int local[8]; int sum = 0;
#pragma unroll
    for (int k = 0; k < 8; ++k) { local[k] = hist[t * 8 + k]; sum += local[k]; }
    int incl = sum;
    for (int d = 1; d < 64; d <<= 1) {
        int n = __shfl_up(incl, d);
        if (lane >= d) incl += n;
    }
    if (lane == 63) wsum[wave] = incl;
    __syncthreads();
    if (t < 16) {
        int v = wsum[t], inc2 = v;
        for (int d = 1; d < 16; d <<= 1) {
            int n = __shfl_up(inc2, d);
            if (t >= d) inc2 += n;
        }
        wexcl[t] = inc2 - v;
    }
    __syncthreads();
    int run = wexcl[wave] + incl - sum;       // exclusive base for this thread's buckets
#pragma unroll
    for (int k = 0; k < 8; ++k) {
        offs[t * 8 + k] = run;
        cursor[t * 8 + k] = run;
        run += local[k];
    }
    if (t == 1023) offs[NB] = run;            // == NN
}

__global__ __launch_bounds__(256) void kscatter(const float* __restrict__ yt,
                                                const float* __restrict__ pred,
                                                int* __restrict__ cursor,
                                                float* __restrict__ ybkt,
                                                float* __restrict__ a2bkt) {
    int i = blockIdx.x * 256 + threadIdx.x;
    float y = yt[i];
    int b = min(max((int)(y * 8192.0f), 0), NB - 1);
    int pos = atomicAdd(&cursor[b], 1);       // device-scope, cross-XCD safe
    ybkt[pos] = y;
    a2bkt[pos] = pred[i] * A2SCALE;
}

// ---------------------------------------------------------------------------
// Kernel: chunk-partial masked max + logsumexp over the sorted prefix.
// (byte-identical logic to round 5 — isolates the sort fix)
// ---------------------------------------------------------------------------
__global__ __launch_bounds__(BLOCK) void pro_main(const float* __restrict__ ybkt,
                                                  const float* __restrict__ a2bkt,
                                                  const int* __restrict__ offs,
                                                  float2* __restrict__ partial) {
    const int t = threadIdx.x;
    const int rg = blockIdx.x >> 2;
    const int c  = blockIdx.x & 3;
    const int j0 = c * CH;
    const int wave = t >> 6, lane = t & 63;
    const int row0 = rg * 16 + wave * 4;

    // whole-block inactive test (end is monotone in sorted position)
    {
        float xl = ybkt[rg * 16 + 15];
        int bl = min((int)(xl * 8192.0f), NB - 1);
        if (offs[bl + 1] <= j0) {
            if (lane == 0) {
#pragma unroll
                for (int r = 0; r < 4; ++r)
                    partial[c * NN + row0 + r] = make_float2(-INFINITY, 0.0f);
            }
            return;                           // uniform: no syncthreads skipped
        }
    }

    float x[4], M[4];
#pragma unroll
    for (int r = 0; r < 4; ++r) { x[r] = ybkt[row0 + r]; M[r] = -INFINITY; }
    int u0, end3;
    {
        int b0 = min((int)(x[0] * 8192.0f), NB - 1);
        u0 = (b0 > 0) ? offs[b0 - 1] : 0;     // below this: valid for ALL 4 rows
        int b3 = min((int)(x[3] * 8192.0f), NB - 1);
        end3 = offs[b3 + 1];                  // at/after this: invalid for all
    }
    int lo = min(max(u0 - j0, 0), CH);
    const int nbi = lo >> 7;                  // full 128-elem unmasked iters
    lo = nbi << 7;
    const int hi = min(max(end3 - j0, lo), CH);
    const int stage_n = min(CH, (hi + 127) & ~127);

    __shared__ float y_s[CH];                 // 8 KB
    __shared__ float4 ac_s[CH / 2];           // 16 KB: (a0, a0*y0, a1, a1*y1)
    const float4* yb4 = (const float4*)(ybkt + j0);
    const float4* ab4 = (const float4*)(a2bkt + j0);
    float4* ys4 = (float4*)y_s;
    for (int i = t; i < stage_n / 4; i += BLOCK) {
        float4 y4 = yb4[i];
        float4 a4 = ab4[i];
        ys4[i] = y4;
        ac_s[2 * i]     = make_float4(a4.x, a4.x * y4.x, a4.y, a4.y * y4.y);
        ac_s[2 * i + 1] = make_float4(a4.z, a4.z * y4.z, a4.w, a4.w * y4.w);
    }
    __syncthreads();

    // ---- pass 1: max of L = fma(a, x, -c) over the valid set ----
    for (int i = 0; i < nbi; ++i) {
        float4 v = ac_s[i * 64 + lane];       // elems 2*(i*64+lane), +1
#pragma unroll
        for (int r = 0; r < 4; ++r) {
            float L0 = __builtin_fmaf(v.x, x[r], -v.y);
            float L1 = __builtin_fmaf(v.z, x[r], -v.w);
            M[r] = fmaxf(M[r], fmaxf(L0, L1));
        }
    }
    for (int base = lo; base < hi; base += 128) {   // straddle: exact compare
        int e = base + lane * 2;
        float y0 = y_s[e], y1 = y_s[e + 1];
        float4 v = ac_s[(base >> 1) + lane];
#pragma unroll
        for (int r = 0; r < 4; ++r) {
            float W0 = x[r] - y0, W1 = x[r] - y1;
            float L0 = __builtin_fmaf(v.x, x[r], -v.y);
            float L1 = __builtin_fmaf(v.z, x[r], -v.w);
            L0 = (W0 > EPSF) ? L0 : -INFINITY;
            L1 = (W1 > EPSF) ? L1 : -INFINITY;
            M[r] = fmaxf(M[r], fmaxf(L0, L1));
        }
    }
#pragma unroll
    for (int r = 0; r < 4; ++r)
        for (int m = 1; m < 64; m <<= 1) M[r] = fmaxf(M[r], __shfl_xor(M[r], m));

    // ---- pass 2: sum exp2(L - M) over the same set ----
    float s[4] = {0.f, 0.f, 0.f, 0.f};
    for (int i = 0; i < nbi; ++i) {
        float4 v = ac_s[i * 64 + lane];
#pragma unroll
        for (int r = 0; r < 4; ++r) {
            float t0 = __builtin_fmaf(v.x, x[r], -v.y) - M[r];
            float t1 = __builtin_fmaf(v.z, x[r], -v.w) - M[r];
            s[r] += exp2f(t0) + exp2f(t1);
        }
    }
    for (int base = lo; base < hi; base += 128) {
        int e = base + lane * 2;
        float y0 = y_s[e], y1 = y_s[e + 1];
        float4 v = ac_s[(base >> 1) + lane];
#pragma unroll
        for (int r = 0; r < 4; ++r) {
            float W0 = x[r] - y0, W1 = x[r] - y1;
            float t0 = __builtin_fmaf(v.x, x[r], -v.y) - M[r];
            float t1 = __builtin_fmaf(v.z, x[r], -v.w) - M[r];
            t0 = (W0 > EPSF) ? t0 : -INFINITY;
            t1 = (W1 > EPSF) ? t1 : -INFINITY;
            s[r] += exp2f(t0) + exp2f(t1);
        }
    }
#pragma unroll
    for (int r = 0; r < 4; ++r)
        for (int m = 1; m < 64; m <<= 1) s[r] += __shfl_xor(s[r], m);

    if (lane == 0) {
#pragma unroll
        for (int r = 0; r < 4; ++r)
            partial[c * NN + row0 + r] = make_float2(M[r], s[r]);
    }
}

// ---------------------------------------------------------------------------
// Finalize: ymin, per-row combine of 4 chunk partials, epilogue, final scalar.
// ---------------------------------------------------------------------------
__global__ __launch_bounds__(1024) void finalize(const float* __restrict__ ybkt,
                                                 const float* __restrict__ a2bkt,
                                                 const float2* __restrict__ partial,
                                                 float* __restrict__ out) {
    __shared__ float redm[16];
    __shared__ float2 red2[16];
    __shared__ float bmin;
    const int t = threadIdx.x, lane = t & 63, wave = t >> 6;

    float mn = INFINITY;
    for (int i = t; i < NN; i += 1024) mn = fminf(mn, ybkt[i]);
#pragma unroll
    for (int m = 1; m < 64; m <<= 1) mn = fminf(mn, __shfl_xor(mn, m));
    if (lane == 0) redm[wave] = mn;
    __syncthreads();
    if (t == 0) {
        float v = redm[0];
        for (int i = 1; i < 16; ++i) v = fminf(v, redm[i]);
        bmin = v;
    }
    __syncthreads();
    const float yt_min = bmin;

    float wtot = 0.f, wcnt = 0.f;
    for (int p = t; p < NN; p += 1024) {
        float x = ybkt[p];
        float w = x - yt_min;                 // == weight_k (max masked gap)
        float lp = a2bkt[p] * w;              // logit_pos, log2-scaled
        float2 pc[CHUNKS];
        float M = lp;
#pragma unroll
        for (int c = 0; c < CHUNKS; ++c) {
            pc[c] = partial[c * NN + p];
            M = fmaxf(M, pc[c].x);
        }
        float sum = exp2f(lp - M);
#pragma unroll
        for (int c = 0; c < CHUNKS; ++c) sum += pc[c].y * exp2f(pc[c].x - M);
        float logp = (lp - M) * LN2f - __logf(sum);
        if (w > EPSF) { wtot += logp; wcnt += 1.f; }
    }
#pragma unroll
    for (int m = 1; m < 64; m <<= 1) { wtot += __shfl_xor(wtot, m); wcnt += __shfl_xor(wcnt, m); }
    if (lane == 0) red2[wave] = make_float2(wtot, wcnt);
    __syncthreads();
    if (t == 0) {
        float bt = 0.f, bc = 0.f;
        for (int i = 0; i < 16; ++i) { bt += red2[i].x; bc += red2[i].y; }
        out[0] = (bc > 0.f) ? (-bt / bc) : 0.f;
    }
}

extern "C" void kernel_launch(void* const* d_in, const int* in_sizes, int n_in,
                              void* d_out, int out_size, void* d_ws, size_t ws_size,
                              hipStream_t stream) {
    const float* pred = (const float*)d_in[0];  // predict_similarity
    const float* yt   = (const float*)d_in[1];  // true_similarity

    float* ybkt   = (float*)d_ws;               // [NN]
    float* a2bkt  = ybkt + NN;                  // [NN]
    int*   offs   = (int*)(a2bkt + NN);         // [NN+2]
    int*   hist   = offs + NN + 2;              // [NB]
    int*   cursor = hist + NB;                  // [NB]
    float2* partial = (float2*)(cursor + NB);   // [CHUNKS][NN] — fully overwritten

    hipMemsetAsync(hist, 0, NB * sizeof(int), stream);
    khist<<<NN / 256, 256, 0, stream>>>(yt, hist);
    kscan<<<1, 1024, 0, stream>>>(hist, offs, cursor);
    kscatter<<<NN / 256, 256, 0, stream>>>(yt, pred, cursor, ybkt, a2bkt);
    pro_main<<<RG * CHUNKS, BLOCK, 0, stream>>>(ybkt, a2bkt, offs, partial);
    finalize<<<1, 1024, 0, stream>>>(ybkt, a2bkt, partial, (float*)d_out);
}